// Round 1
// baseline (873.531 us; speedup 1.0000x reference)
//
#include <hip/hip_runtime.h>
#include <math.h>

#define W 128
#define H 128
#define HW 16384
#define CIN 96
#define COUT 96
#define BATCH 16

// ---------------------------------------------------------------------------
// Weight pre-transpose:
//   wAT[c][kk][28]: o-major contiguous (o<18: offset_w, 18..26: mask_w, 27: pad)
//   wBT[k][c][96]:  main conv weight transposed so (k,c) row is o-contiguous
// ---------------------------------------------------------------------------
__global__ void prep_weights(const float* __restrict__ weight,
                             const float* __restrict__ offset_w,
                             const float* __restrict__ mask_w,
                             float* __restrict__ wAT,
                             float* __restrict__ wBT) {
  int idx = blockIdx.x * blockDim.x + threadIdx.x;
  const int nA = CIN * 9 * 28;
  if (idx < nA) {
    int o = idx % 28;
    int rest = idx / 28;
    int kk = rest % 9;
    int c = rest / 9;
    float v = 0.f;
    if (o < 18)      v = offset_w[(o * CIN + c) * 9 + kk];
    else if (o < 27) v = mask_w[((o - 18) * CIN + c) * 9 + kk];
    wAT[idx] = v;
  } else {
    int j = idx - nA;
    if (j < 9 * CIN * COUT) {
      int o = j % COUT;
      int rest = j / COUT;
      int c = rest % CIN;
      int k = rest / CIN;
      wBT[j] = weight[(o * CIN + c) * 9 + k];
    }
  }
}

// ---------------------------------------------------------------------------
// Kernel A: offset/mask conv. One thread per output pixel, 27 accumulators.
// Weights read through wave-uniform addresses -> scalar loads; VALU does
// only v_fmac_f32.  offm layout: [b][27][H][W]  (0..17 offsets, 18..26 mask
// with sigmoid applied).
// ---------------------------------------------------------------------------
__global__ __launch_bounds__(256) void offmask_kernel(
    const float* __restrict__ x, const float* __restrict__ wAT,
    const float* __restrict__ offset_b, const float* __restrict__ mask_b,
    float* __restrict__ offm) {
  int w = threadIdx.x & 127;
  int hsub = threadIdx.x >> 7;
  int bh = blockIdx.x;
  int b = bh >> 6;
  int h = ((bh & 63) << 1) + hsub;

  float acc[27];
#pragma unroll
  for (int o = 0; o < 27; ++o) acc[o] = 0.f;

  const float* xb = x + (size_t)b * CIN * HW;
  for (int c = 0; c < CIN; ++c) {
    const float* xp = xb + c * HW;
    float xv[9];
#pragma unroll
    for (int dy = 0; dy < 3; ++dy) {
      int yy = h + dy - 1;
      bool yok = (unsigned)yy < (unsigned)H;
#pragma unroll
      for (int dx = 0; dx < 3; ++dx) {
        int xx = w + dx - 1;
        bool ok = yok && ((unsigned)xx < (unsigned)W);
        xv[dy * 3 + dx] = ok ? xp[yy * W + xx] : 0.f;
      }
    }
    const float* wp = wAT + c * 9 * 28;
#pragma unroll
    for (int kk = 0; kk < 9; ++kk) {
      float v = xv[kk];
#pragma unroll
      for (int o = 0; o < 27; ++o)
        acc[o] = fmaf(v, wp[kk * 28 + o], acc[o]);
    }
  }

  size_t pix = (size_t)h * W + w;
  float* ob = offm + (size_t)b * 27 * HW;
#pragma unroll
  for (int o = 0; o < 18; ++o)
    ob[(size_t)o * HW + pix] = acc[o] + offset_b[o];
#pragma unroll
  for (int kk = 0; kk < 9; ++kk) {
    float v = acc[18 + kk] + mask_b[kk];
    ob[(size_t)(18 + kk) * HW + pix] = 1.f / (1.f + expf(-v));
  }
}

// ---------------------------------------------------------------------------
// Kernel B: main deformable conv. Block = 64 pixels (lane = w) x 4 waves.
// Per k: waves cooperatively build samp[96][64] (bilinear, mask folded into
// the 4 tap weights), then each wave computes its 24 output channels with
// scalar-loaded weights.
// ---------------------------------------------------------------------------
__global__ __launch_bounds__(256) void deform_kernel(
    const float* __restrict__ x, const float* __restrict__ offm,
    const float* __restrict__ wBT, const float* __restrict__ bias,
    float* __restrict__ out) {
  __shared__ float samp[CIN][64];

  int t = threadIdx.x;
  int lane = t & 63;
  int wv = __builtin_amdgcn_readfirstlane(t >> 6);

  int blk = blockIdx.x;
  int b = blk >> 8;
  int rem = blk & 255;
  int h = rem >> 1;
  int w0 = (rem & 1) << 6;
  int w = w0 + lane;

  float acc[24];
#pragma unroll
  for (int o = 0; o < 24; ++o) acc[o] = 0.f;

  const float* xb = x + (size_t)b * CIN * HW;
  const float* ob = offm + (size_t)b * 27 * HW;
  size_t pix = (size_t)h * W + w;

  for (int k = 0; k < 9; ++k) {
    int ki = k / 3, kj = k % 3;
    float dy = ob[(size_t)(2 * k) * HW + pix];
    float dx = ob[(size_t)(2 * k + 1) * HW + pix];
    float m  = ob[(size_t)(18 + k) * HW + pix];

    float py = (float)(h - 1 + ki) + dy;
    float px = (float)(w - 1 + kj) + dx;
    float fy = floorf(py), fx = floorf(px);
    float wy = py - fy, wx = px - fx;
    int iy0 = (int)fy, ix0 = (int)fx;
    int iy1 = iy0 + 1, ix1 = ix0 + 1;
    bool y0ok = (unsigned)iy0 < (unsigned)H;
    bool y1ok = (unsigned)iy1 < (unsigned)H;
    bool x0ok = (unsigned)ix0 < (unsigned)W;
    bool x1ok = (unsigned)ix1 < (unsigned)W;
    float w00 = (y0ok && x0ok) ? (1.f - wy) * (1.f - wx) * m : 0.f;
    float w01 = (y0ok && x1ok) ? (1.f - wy) * wx * m : 0.f;
    float w10 = (y1ok && x0ok) ? wy * (1.f - wx) * m : 0.f;
    float w11 = (y1ok && x1ok) ? wy * wx * m : 0.f;
    int cy0 = min(max(iy0, 0), H - 1), cy1 = min(max(iy1, 0), H - 1);
    int cx0 = min(max(ix0, 0), W - 1), cx1 = min(max(ix1, 0), W - 1);
    int o00 = cy0 * W + cx0, o01 = cy0 * W + cx1;
    int o10 = cy1 * W + cx0, o11 = cy1 * W + cx1;

    // gather phase: this wave fills channels [wv*24, wv*24+24)
#pragma unroll 4
    for (int cc = 0; cc < 24; ++cc) {
      int c = wv * 24 + cc;
      const float* xp = xb + (size_t)c * HW;
      float v = w00 * xp[o00] + w01 * xp[o01] + w10 * xp[o10] + w11 * xp[o11];
      samp[c][lane] = v;
    }
    __syncthreads();

    // GEMM phase: 24 output channels per wave, scalar weights
    const float* wk = wBT + (size_t)k * CIN * COUT + wv * 24;
#pragma unroll 2
    for (int c = 0; c < CIN; ++c) {
      float v = samp[c][lane];
      const float* sw = wk + c * COUT;
#pragma unroll
      for (int o = 0; o < 24; ++o)
        acc[o] = fmaf(v, sw[o], acc[o]);
    }
    __syncthreads();
  }

  float* outb = out + (size_t)b * COUT * HW;
#pragma unroll
  for (int o = 0; o < 24; ++o)
    outb[(size_t)(wv * 24 + o) * HW + pix] = acc[o] + bias[wv * 24 + o];
}

// ---------------------------------------------------------------------------
extern "C" void kernel_launch(void* const* d_in, const int* in_sizes, int n_in,
                              void* d_out, int out_size, void* d_ws, size_t ws_size,
                              hipStream_t stream) {
  const float* x        = (const float*)d_in[0];
  const float* weight   = (const float*)d_in[1];
  const float* bias     = (const float*)d_in[2];
  const float* offset_w = (const float*)d_in[3];
  const float* offset_b = (const float*)d_in[4];
  const float* mask_w   = (const float*)d_in[5];
  const float* mask_b   = (const float*)d_in[6];
  float* out = (float*)d_out;

  float* offm = (float*)d_ws;                         // 16*27*16384 floats
  float* wAT  = offm + (size_t)BATCH * 27 * HW;       // 96*9*28
  float* wBT  = wAT + CIN * 9 * 28;                   // 9*96*96

  const int nPrep = CIN * 9 * 28 + 9 * CIN * COUT;
  prep_weights<<<(nPrep + 255) / 256, 256, 0, stream>>>(weight, offset_w, mask_w, wAT, wBT);
  offmask_kernel<<<BATCH * (H / 2), 256, 0, stream>>>(x, wAT, offset_b, mask_b, offm);
  deform_kernel<<<BATCH * H * (W / 64), 256, 0, stream>>>(x, offm, wBT, bias, out);
}

// Round 2
// 777.649 us; speedup vs baseline: 1.1233x; 1.1233x over previous
//
#include <hip/hip_runtime.h>
#include <math.h>

#define W 128
#define H 128
#define HW 16384
#define CIN 96
#define COUT 96
#define BATCH 16

typedef __bf16 bf16x8 __attribute__((ext_vector_type(8)));
typedef float f32x4 __attribute__((ext_vector_type(4)));

// ---------------------------------------------------------------------------
// Weight prep:
//   wAT[c][kk][28] f32: o-contiguous (o<18: offset_w, 18..26: mask_w, 27 pad)
//   wBT_bf[tap][o][c] bf16: main weight, K(=c)-contiguous rows per output ch,
//     laid out for direct b-fragment loads of mfma_f32_16x16x32_bf16.
// ---------------------------------------------------------------------------
__global__ void prep_weights(const float* __restrict__ weight,
                             const float* __restrict__ offset_w,
                             const float* __restrict__ mask_w,
                             float* __restrict__ wAT,
                             __bf16* __restrict__ wBT_bf) {
  int idx = blockIdx.x * blockDim.x + threadIdx.x;
  const int nA = CIN * 9 * 28;
  if (idx < nA) {
    int o = idx % 28;
    int rest = idx / 28;
    int kk = rest % 9;
    int c = rest / 9;
    float v = 0.f;
    if (o < 18)      v = offset_w[(o * CIN + c) * 9 + kk];
    else if (o < 27) v = mask_w[((o - 18) * CIN + c) * 9 + kk];
    wAT[idx] = v;
  } else {
    int j = idx - nA;
    if (j < 9 * CIN * COUT) {
      int c = j % CIN;
      int o = (j / CIN) % COUT;
      int tap = j / (CIN * COUT);
      wBT_bf[j] = (__bf16)weight[(o * CIN + c) * 9 + tap];
    }
  }
}

// ---------------------------------------------------------------------------
// Kernel A: offset/mask conv (f32 VALU). One thread per pixel, 27 accs.
// offm layout: [b][27][H][W] (0..17 offsets, 18..26 sigmoid(mask)).
// ---------------------------------------------------------------------------
__global__ __launch_bounds__(256) void offmask_kernel(
    const float* __restrict__ x, const float* __restrict__ wAT,
    const float* __restrict__ offset_b, const float* __restrict__ mask_b,
    float* __restrict__ offm) {
  int w = threadIdx.x & 127;
  int hsub = threadIdx.x >> 7;
  int bh = blockIdx.x;
  int b = bh >> 6;
  int h = ((bh & 63) << 1) + hsub;

  float acc[27];
#pragma unroll
  for (int o = 0; o < 27; ++o) acc[o] = 0.f;

  const float* xb = x + (size_t)b * CIN * HW;
  for (int c = 0; c < CIN; ++c) {
    const float* xp = xb + c * HW;
    float xv[9];
#pragma unroll
    for (int dy = 0; dy < 3; ++dy) {
      int yy = h + dy - 1;
      bool yok = (unsigned)yy < (unsigned)H;
#pragma unroll
      for (int dx = 0; dx < 3; ++dx) {
        int xx = w + dx - 1;
        bool ok = yok && ((unsigned)xx < (unsigned)W);
        xv[dy * 3 + dx] = ok ? xp[yy * W + xx] : 0.f;
      }
    }
    const float* wp = wAT + c * 9 * 28;
#pragma unroll
    for (int kk = 0; kk < 9; ++kk) {
      float v = xv[kk];
#pragma unroll
      for (int o = 0; o < 27; ++o)
        acc[o] = fmaf(v, wp[kk * 28 + o], acc[o]);
    }
  }

  size_t pix = (size_t)h * W + w;
  float* ob = offm + (size_t)b * 27 * HW;
#pragma unroll
  for (int o = 0; o < 18; ++o)
    ob[(size_t)o * HW + pix] = acc[o] + offset_b[o];
#pragma unroll
  for (int kk = 0; kk < 9; ++kk) {
    float v = acc[18 + kk] + mask_b[kk];
    ob[(size_t)(18 + kk) * HW + pix] = 1.f / (1.f + expf(-v));
  }
}

// ---------------------------------------------------------------------------
// Kernel B: deformable conv, bf16 MFMA GEMM.
// Block = 64 pixels (lane = w) x 4 waves. Per tap k:
//   gather: wave wv fills samp[pix][c] for c in [wv*24, wv*24+24) as bf16,
//           mask+validity folded into the 4 bilinear tap weights (f32).
//   GEMM:   wave wv owns pixel rows [wv*16, wv*16+16) x all 96 out channels:
//           6 N-tiles x 3 K-steps of mfma_f32_16x16x32_bf16.
// A-frag: lane reads samp[m0+(l&15)][ks*32+(l>>4)*8 ..+8]  (ds_read_b128)
// B-frag: lane reads wBT_bf[tap][n0+(l&15)][ks*32+(l>>4)*8 ..+8] (global, L2)
// C/D: row(pixel) = (l>>4)*4+r, col(out ch) = l&15   [m89-verified layout]
// ---------------------------------------------------------------------------
__global__ __launch_bounds__(256) void deform_kernel(
    const float* __restrict__ x, const float* __restrict__ offm,
    const __bf16* __restrict__ wBT, const float* __restrict__ bias,
    float* __restrict__ out) {
  __shared__ __bf16 samp[64][104];   // pitch 104 bf16 = 208 B (16B-aligned rows)

  int t = threadIdx.x;
  int lane = t & 63;
  int wv = __builtin_amdgcn_readfirstlane(t >> 6);

  // XCD-chunked bijective swizzle (nwg=4096, 4096%8==0): blocks resident on
  // the same XCD get consecutive (b,h) work -> x-row reuse in that XCD's L2.
  int bid = (int)blockIdx.x;
  int nb = (bid & 7) * 512 + (bid >> 3);
  int b = nb >> 8;
  int rem = nb & 255;
  int h = rem >> 1;
  int w0 = (rem & 1) << 6;
  int w = w0 + lane;

  f32x4 acc[6];
#pragma unroll
  for (int nt = 0; nt < 6; ++nt) acc[nt] = (f32x4){0.f, 0.f, 0.f, 0.f};

  const float* xb = x + (size_t)b * CIN * HW;
  const float* ob = offm + (size_t)b * 27 * HW;
  size_t pix = (size_t)h * W + w;

  const __bf16* sampb = &samp[0][0] + ((wv * 16 + (lane & 15)) * 104 + (lane >> 4) * 8);
  const __bf16* wb = wBT + ((lane & 15) * 96 + (lane >> 4) * 8);

  for (int k = 0; k < 9; ++k) {
    int ki = k / 3, kj = k % 3;
    float dy = ob[(size_t)(2 * k) * HW + pix];
    float dx = ob[(size_t)(2 * k + 1) * HW + pix];
    float m  = ob[(size_t)(18 + k) * HW + pix];

    float py = (float)(h - 1 + ki) + dy;
    float px = (float)(w - 1 + kj) + dx;
    float fy = floorf(py), fx = floorf(px);
    float wy = py - fy, wx = px - fx;
    int iy0 = (int)fy, ix0 = (int)fx;
    int iy1 = iy0 + 1, ix1 = ix0 + 1;
    bool y0ok = (unsigned)iy0 < (unsigned)H;
    bool y1ok = (unsigned)iy1 < (unsigned)H;
    bool x0ok = (unsigned)ix0 < (unsigned)W;
    bool x1ok = (unsigned)ix1 < (unsigned)W;
    float w00 = (y0ok && x0ok) ? (1.f - wy) * (1.f - wx) * m : 0.f;
    float w01 = (y0ok && x1ok) ? (1.f - wy) * wx * m : 0.f;
    float w10 = (y1ok && x0ok) ? wy * (1.f - wx) * m : 0.f;
    float w11 = (y1ok && x1ok) ? wy * wx * m : 0.f;
    int cy0 = min(max(iy0, 0), H - 1), cy1 = min(max(iy1, 0), H - 1);
    int cx0 = min(max(ix0, 0), W - 1), cx1 = min(max(ix1, 0), W - 1);
    int o00 = cy0 * W + cx0, o01 = cy0 * W + cx1;
    int o10 = cy1 * W + cx0, o11 = cy1 * W + cx1;

    // ---- gather phase: 24 channels -> 3x ds_write_b128 of 8 bf16 ----
#pragma unroll
    for (int blk = 0; blk < 3; ++blk) {
      int c0 = wv * 24 + blk * 8;
      const float* xp = xb + (size_t)c0 * HW;
      bf16x8 av;
#pragma unroll
      for (int cc = 0; cc < 8; ++cc) {
        const float* p = xp + (size_t)cc * HW;
        float v = w00 * p[o00] + w01 * p[o01] + w10 * p[o10] + w11 * p[o11];
        av[cc] = (__bf16)v;
      }
      *(bf16x8*)&samp[lane][c0] = av;
    }
    __syncthreads();

    // ---- GEMM phase: 6 N-tiles x 3 K-steps ----
    const __bf16* bt = wb + k * (COUT * CIN);
    bf16x8 a0 = *(const bf16x8*)(sampb);
    bf16x8 a1 = *(const bf16x8*)(sampb + 32);
    bf16x8 a2 = *(const bf16x8*)(sampb + 64);
#pragma unroll
    for (int nt = 0; nt < 6; ++nt) {
      const __bf16* bp = bt + nt * 16 * CIN;
      bf16x8 b0 = *(const bf16x8*)(bp);
      bf16x8 b1 = *(const bf16x8*)(bp + 32);
      bf16x8 b2 = *(const bf16x8*)(bp + 64);
      acc[nt] = __builtin_amdgcn_mfma_f32_16x16x32_bf16(a0, b0, acc[nt], 0, 0, 0);
      acc[nt] = __builtin_amdgcn_mfma_f32_16x16x32_bf16(a1, b1, acc[nt], 0, 0, 0);
      acc[nt] = __builtin_amdgcn_mfma_f32_16x16x32_bf16(a2, b2, acc[nt], 0, 0, 0);
    }
    __syncthreads();
  }

  // ---- epilogue: D row = pixel, col = out channel ----
  float* outb = out + (size_t)b * COUT * HW;
  int prow = w0 + wv * 16 + ((lane >> 4) << 2);
#pragma unroll
  for (int nt = 0; nt < 6; ++nt) {
    int ch = nt * 16 + (lane & 15);
    float bv = bias[ch];
    float* op = outb + (size_t)ch * HW + (size_t)h * W + prow;
    float4 o4;
    o4.x = acc[nt][0] + bv;
    o4.y = acc[nt][1] + bv;
    o4.z = acc[nt][2] + bv;
    o4.w = acc[nt][3] + bv;
    *(float4*)op = o4;
  }
}

// ---------------------------------------------------------------------------
extern "C" void kernel_launch(void* const* d_in, const int* in_sizes, int n_in,
                              void* d_out, int out_size, void* d_ws, size_t ws_size,
                              hipStream_t stream) {
  const float* x        = (const float*)d_in[0];
  const float* weight   = (const float*)d_in[1];
  const float* bias     = (const float*)d_in[2];
  const float* offset_w = (const float*)d_in[3];
  const float* offset_b = (const float*)d_in[4];
  const float* mask_w   = (const float*)d_in[5];
  const float* mask_b   = (const float*)d_in[6];
  float* out = (float*)d_out;

  float* offm = (float*)d_ws;                          // 16*27*16384 f32
  float* wAT  = offm + (size_t)BATCH * 27 * HW;        // 96*9*28 f32
  __bf16* wBT_bf = (__bf16*)(wAT + CIN * 9 * 28);      // 9*96*96 bf16

  const int nPrep = CIN * 9 * 28 + 9 * CIN * COUT;
  prep_weights<<<(nPrep + 255) / 256, 256, 0, stream>>>(weight, offset_w, mask_w, wAT, wBT_bf);
  offmask_kernel<<<BATCH * (H / 2), 256, 0, stream>>>(x, wAT, offset_b, mask_b, offm);
  deform_kernel<<<BATCH * H * (W / 64), 256, 0, stream>>>(x, offm, wBT_bf, bias, out);
}

// Round 3
// 777.103 us; speedup vs baseline: 1.1241x; 1.0007x over previous
//
#include <hip/hip_runtime.h>
#include <math.h>

#define W 128
#define H 128
#define HW 16384
#define CIN 96
#define COUT 96
#define BATCH 16

typedef __bf16 bf16x8 __attribute__((ext_vector_type(8)));
typedef float f32x4 __attribute__((ext_vector_type(4)));

// ---------------------------------------------------------------------------
// Weight prep (unchanged from R2):
//   wAT[c][kk][28] f32: o-contiguous (o<18: offset_w, 18..26: mask_w, 27 pad)
//   wBT_bf[tap][o][c] bf16: main weight, c-contiguous per output row.
// ---------------------------------------------------------------------------
__global__ void prep_weights(const float* __restrict__ weight,
                             const float* __restrict__ offset_w,
                             const float* __restrict__ mask_w,
                             float* __restrict__ wAT,
                             __bf16* __restrict__ wBT_bf) {
  int idx = blockIdx.x * blockDim.x + threadIdx.x;
  const int nA = CIN * 9 * 28;
  if (idx < nA) {
    int o = idx % 28;
    int rest = idx / 28;
    int kk = rest % 9;
    int c = rest / 9;
    float v = 0.f;
    if (o < 18)      v = offset_w[(o * CIN + c) * 9 + kk];
    else if (o < 27) v = mask_w[((o - 18) * CIN + c) * 9 + kk];
    wAT[idx] = v;
  } else {
    int j = idx - nA;
    if (j < 9 * CIN * COUT) {
      int c = j % CIN;
      int o = (j / CIN) % COUT;
      int tap = j / (CIN * COUT);
      wBT_bf[j] = (__bf16)weight[(o * CIN + c) * 9 + tap];
    }
  }
}

// ---------------------------------------------------------------------------
// Kernel A: offset/mask conv (f32 VALU), unchanged from R2.
// ---------------------------------------------------------------------------
__global__ __launch_bounds__(256) void offmask_kernel(
    const float* __restrict__ x, const float* __restrict__ wAT,
    const float* __restrict__ offset_b, const float* __restrict__ mask_b,
    float* __restrict__ offm) {
  int w = threadIdx.x & 127;
  int hsub = threadIdx.x >> 7;
  int bh = blockIdx.x;
  int b = bh >> 6;
  int h = ((bh & 63) << 1) + hsub;

  float acc[27];
#pragma unroll
  for (int o = 0; o < 27; ++o) acc[o] = 0.f;

  const float* xb = x + (size_t)b * CIN * HW;
  for (int c = 0; c < CIN; ++c) {
    const float* xp = xb + c * HW;
    float xv[9];
#pragma unroll
    for (int dy = 0; dy < 3; ++dy) {
      int yy = h + dy - 1;
      bool yok = (unsigned)yy < (unsigned)H;
#pragma unroll
      for (int dx = 0; dx < 3; ++dx) {
        int xx = w + dx - 1;
        bool ok = yok && ((unsigned)xx < (unsigned)W);
        xv[dy * 3 + dx] = ok ? xp[yy * W + xx] : 0.f;
      }
    }
    const float* wp = wAT + c * 9 * 28;
#pragma unroll
    for (int kk = 0; kk < 9; ++kk) {
      float v = xv[kk];
#pragma unroll
      for (int o = 0; o < 27; ++o)
        acc[o] = fmaf(v, wp[kk * 28 + o], acc[o]);
    }
  }

  size_t pix = (size_t)h * W + w;
  float* ob = offm + (size_t)b * 27 * HW;
#pragma unroll
  for (int o = 0; o < 18; ++o)
    ob[(size_t)o * HW + pix] = acc[o] + offset_b[o];
#pragma unroll
  for (int kk = 0; kk < 9; ++kk) {
    float v = acc[18 + kk] + mask_b[kk];
    ob[(size_t)(18 + kk) * HW + pix] = 1.f / (1.f + expf(-v));
  }
}

// ---------------------------------------------------------------------------
// Kernel B v3: software-pipelined deformable conv.
//   - double-buffered samp LDS, ONE barrier per tap
//   - gather for tap k+1 issued during GEMM of tap k (issue-early/write-late)
//   - offm prefetched two taps ahead; tap addresses computed one tap ahead
//   - VMEM issue order per third: [b-frags][gather chunk] so in-order vmcnt
//     never forces young gather loads before MFMA operand consumption
// ---------------------------------------------------------------------------

// computes o00..o11 / w00c..w11c (declared by caller) from (kk, dy, dx, m)
#define TAP_ADDR(kk, dyv, dxv, mv)                                     \
  {                                                                    \
    int ki = (kk) / 3, kj = (kk) % 3;                                  \
    float py = (float)(h - 1 + ki) + (dyv);                            \
    float px = (float)(w - 1 + kj) + (dxv);                            \
    float fy = floorf(py), fx = floorf(px);                            \
    float wyf = py - fy, wxf = px - fx;                                \
    int iy0 = (int)fy, ix0 = (int)fx;                                  \
    int iy1 = iy0 + 1, ix1 = ix0 + 1;                                  \
    bool y0ok = (unsigned)iy0 < (unsigned)H;                           \
    bool y1ok = (unsigned)iy1 < (unsigned)H;                           \
    bool x0ok = (unsigned)ix0 < (unsigned)W;                           \
    bool x1ok = (unsigned)ix1 < (unsigned)W;                           \
    w00c = (y0ok && x0ok) ? (1.f - wyf) * (1.f - wxf) * (mv) : 0.f;    \
    w01c = (y0ok && x1ok) ? (1.f - wyf) * wxf * (mv) : 0.f;            \
    w10c = (y1ok && x0ok) ? wyf * (1.f - wxf) * (mv) : 0.f;            \
    w11c = (y1ok && x1ok) ? wyf * wxf * (mv) : 0.f;                    \
    int cy0 = min(max(iy0, 0), H - 1), cy1 = min(max(iy1, 0), H - 1);  \
    int cx0 = min(max(ix0, 0), W - 1), cx1 = min(max(ix1, 0), W - 1);  \
    o00 = cy0 * W + cx0; o01 = cy0 * W + cx1;                          \
    o10 = cy1 * W + cx0; o11 = cy1 * W + cx1;                          \
  }

__global__ __launch_bounds__(256, 2) void deform_kernel(
    const float* __restrict__ x, const float* __restrict__ offm,
    const __bf16* __restrict__ wBT, const float* __restrict__ bias,
    float* __restrict__ out) {
  __shared__ __bf16 samp[2][64][104];  // double buffer, pitch 104 bf16 (208 B)

  int t = threadIdx.x;
  int lane = t & 63;
  int wv = __builtin_amdgcn_readfirstlane(t >> 6);

  // XCD-chunked bijective swizzle (nwg=4096 % 8 == 0)
  int bid = (int)blockIdx.x;
  int nb = (bid & 7) * 512 + (bid >> 3);
  int b = nb >> 8;
  int rem = nb & 255;
  int h = rem >> 1;
  int w0 = (rem & 1) << 6;
  int w = w0 + lane;

  f32x4 acc[6];
#pragma unroll
  for (int nt = 0; nt < 6; ++nt) acc[nt] = (f32x4){0.f, 0.f, 0.f, 0.f};

  const float* xb = x + (size_t)b * CIN * HW;
  const float* ob = offm + (size_t)b * 27 * HW;
  size_t pix = (size_t)h * W + w;

  const __bf16* wb = wBT + ((lane & 15) * 96 + (lane >> 4) * 8);

  int o00, o01, o10, o11;
  float w00c, w01c, w10c, w11c;

  // ---- prologue: gather tap 0 into buf 0, set up addresses for tap 1 ----
  {
    float dyv = ob[pix];
    float dxv = ob[(size_t)HW + pix];
    float mv  = ob[(size_t)18 * HW + pix];
    TAP_ADDR(0, dyv, dxv, mv);
#pragma unroll
    for (int tt = 0; tt < 3; ++tt) {
      const float* xp = xb + (size_t)(wv * 24 + tt * 8) * HW;
      bf16x8 av;
#pragma unroll
      for (int cc = 0; cc < 8; ++cc) {
        const float* p = xp + (size_t)cc * HW;
        av[cc] = (__bf16)(w00c * p[o00] + w01c * p[o01] +
                          w10c * p[o10] + w11c * p[o11]);
      }
      *(bf16x8*)&samp[0][lane][wv * 24 + tt * 8] = av;
    }
    dyv = ob[(size_t)2 * HW + pix];
    dxv = ob[(size_t)3 * HW + pix];
    mv  = ob[(size_t)19 * HW + pix];
    TAP_ADDR(1, dyv, dxv, mv);
  }
  __syncthreads();

  // ---- main loop: GEMM tap k from buf[k&1]; gather tap k+1 into buf[~k&1] ----
  for (int k = 0; k < 9; ++k) {
    const int cur = k & 1, nxt = cur ^ 1;
    const bool hav = (k < 8);

    // offm prefetch for tap k+2 (oldest in vmcnt queue -> cheap to consume)
    float pdy = 0.f, pdx = 0.f, pm = 0.f;
    if (k < 7) {
      pdy = ob[(size_t)(2 * k + 4) * HW + pix];
      pdx = ob[(size_t)(2 * k + 5) * HW + pix];
      pm  = ob[(size_t)(k + 20) * HW + pix];
    }

    // A-fragments from LDS (lgkm counter, independent of vmcnt)
    const __bf16* arow = &samp[cur][0][0] +
                         ((wv * 16 + (lane & 15)) * 104 + (lane >> 4) * 8);
    bf16x8 a0 = *(const bf16x8*)(arow);
    bf16x8 a1 = *(const bf16x8*)(arow + 32);
    bf16x8 a2 = *(const bf16x8*)(arow + 64);

    const __bf16* bt = wb + k * (COUT * CIN);

    float g0[4][8], g1[4][8], g2[4][8];

    // ================= third 0: N-tiles 0,1 + gather chunk 0 =================
    {
      const __bf16* bp0 = bt;
      const __bf16* bp1 = bt + 16 * CIN;
      bf16x8 b00 = *(const bf16x8*)(bp0);
      bf16x8 b01 = *(const bf16x8*)(bp0 + 32);
      bf16x8 b02 = *(const bf16x8*)(bp0 + 64);
      bf16x8 b10 = *(const bf16x8*)(bp1);
      bf16x8 b11 = *(const bf16x8*)(bp1 + 32);
      bf16x8 b12 = *(const bf16x8*)(bp1 + 64);
      if (hav) {
        const float* xp = xb + (size_t)(wv * 24) * HW;
#pragma unroll
        for (int cc = 0; cc < 8; ++cc) {
          const float* p = xp + (size_t)cc * HW;
          g0[0][cc] = p[o00]; g0[1][cc] = p[o01];
          g0[2][cc] = p[o10]; g0[3][cc] = p[o11];
        }
      }
      acc[0] = __builtin_amdgcn_mfma_f32_16x16x32_bf16(a0, b00, acc[0], 0, 0, 0);
      acc[0] = __builtin_amdgcn_mfma_f32_16x16x32_bf16(a1, b01, acc[0], 0, 0, 0);
      acc[0] = __builtin_amdgcn_mfma_f32_16x16x32_bf16(a2, b02, acc[0], 0, 0, 0);
      acc[1] = __builtin_amdgcn_mfma_f32_16x16x32_bf16(a0, b10, acc[1], 0, 0, 0);
      acc[1] = __builtin_amdgcn_mfma_f32_16x16x32_bf16(a1, b11, acc[1], 0, 0, 0);
      acc[1] = __builtin_amdgcn_mfma_f32_16x16x32_bf16(a2, b12, acc[1], 0, 0, 0);
    }

    // ================= third 1: N-tiles 2,3 + gather chunk 1 =================
    {
      const __bf16* bp0 = bt + 2 * 16 * CIN;
      const __bf16* bp1 = bt + 3 * 16 * CIN;
      bf16x8 b00 = *(const bf16x8*)(bp0);
      bf16x8 b01 = *(const bf16x8*)(bp0 + 32);
      bf16x8 b02 = *(const bf16x8*)(bp0 + 64);
      bf16x8 b10 = *(const bf16x8*)(bp1);
      bf16x8 b11 = *(const bf16x8*)(bp1 + 32);
      bf16x8 b12 = *(const bf16x8*)(bp1 + 64);
      if (hav) {
        const float* xp = xb + (size_t)(wv * 24 + 8) * HW;
#pragma unroll
        for (int cc = 0; cc < 8; ++cc) {
          const float* p = xp + (size_t)cc * HW;
          g1[0][cc] = p[o00]; g1[1][cc] = p[o01];
          g1[2][cc] = p[o10]; g1[3][cc] = p[o11];
        }
      }
      acc[2] = __builtin_amdgcn_mfma_f32_16x16x32_bf16(a0, b00, acc[2], 0, 0, 0);
      acc[2] = __builtin_amdgcn_mfma_f32_16x16x32_bf16(a1, b01, acc[2], 0, 0, 0);
      acc[2] = __builtin_amdgcn_mfma_f32_16x16x32_bf16(a2, b02, acc[2], 0, 0, 0);
      acc[3] = __builtin_amdgcn_mfma_f32_16x16x32_bf16(a0, b10, acc[3], 0, 0, 0);
      acc[3] = __builtin_amdgcn_mfma_f32_16x16x32_bf16(a1, b11, acc[3], 0, 0, 0);
      acc[3] = __builtin_amdgcn_mfma_f32_16x16x32_bf16(a2, b12, acc[3], 0, 0, 0);
      // write-late chunk 0 (its loads covered by third0 MFMAs + third1 issue)
      if (hav) {
        bf16x8 av;
#pragma unroll
        for (int cc = 0; cc < 8; ++cc)
          av[cc] = (__bf16)(w00c * g0[0][cc] + w01c * g0[1][cc] +
                            w10c * g0[2][cc] + w11c * g0[3][cc]);
        *(bf16x8*)&samp[nxt][lane][wv * 24] = av;
      }
    }

    // ================= third 2: N-tiles 4,5 + gather chunk 2 =================
    {
      const __bf16* bp0 = bt + 4 * 16 * CIN;
      const __bf16* bp1 = bt + 5 * 16 * CIN;
      bf16x8 b00 = *(const bf16x8*)(bp0);
      bf16x8 b01 = *(const bf16x8*)(bp0 + 32);
      bf16x8 b02 = *(const bf16x8*)(bp0 + 64);
      bf16x8 b10 = *(const bf16x8*)(bp1);
      bf16x8 b11 = *(const bf16x8*)(bp1 + 32);
      bf16x8 b12 = *(const bf16x8*)(bp1 + 64);
      if (hav) {
        const float* xp = xb + (size_t)(wv * 24 + 16) * HW;
#pragma unroll
        for (int cc = 0; cc < 8; ++cc) {
          const float* p = xp + (size_t)cc * HW;
          g2[0][cc] = p[o00]; g2[1][cc] = p[o01];
          g2[2][cc] = p[o10]; g2[3][cc] = p[o11];
        }
      }
      acc[4] = __builtin_amdgcn_mfma_f32_16x16x32_bf16(a0, b00, acc[4], 0, 0, 0);
      acc[4] = __builtin_amdgcn_mfma_f32_16x16x32_bf16(a1, b01, acc[4], 0, 0, 0);
      acc[4] = __builtin_amdgcn_mfma_f32_16x16x32_bf16(a2, b02, acc[4], 0, 0, 0);
      acc[5] = __builtin_amdgcn_mfma_f32_16x16x32_bf16(a0, b10, acc[5], 0, 0, 0);
      acc[5] = __builtin_amdgcn_mfma_f32_16x16x32_bf16(a1, b11, acc[5], 0, 0, 0);
      acc[5] = __builtin_amdgcn_mfma_f32_16x16x32_bf16(a2, b12, acc[5], 0, 0, 0);
      if (hav) {
        bf16x8 av;
#pragma unroll
        for (int cc = 0; cc < 8; ++cc)
          av[cc] = (__bf16)(w00c * g1[0][cc] + w01c * g1[1][cc] +
                            w10c * g1[2][cc] + w11c * g1[3][cc]);
        *(bf16x8*)&samp[nxt][lane][wv * 24 + 8] = av;
      }
    }

    // tail: write chunk 2, roll addresses to tap k+2, one barrier
    if (hav) {
      bf16x8 av;
#pragma unroll
      for (int cc = 0; cc < 8; ++cc)
        av[cc] = (__bf16)(w00c * g2[0][cc] + w01c * g2[1][cc] +
                          w10c * g2[2][cc] + w11c * g2[3][cc]);
      *(bf16x8*)&samp[nxt][lane][wv * 24 + 16] = av;
    }
    if (k < 7) {
      TAP_ADDR(k + 2, pdy, pdx, pm);
    }
    if (hav) __syncthreads();
  }

  // ---- epilogue: D row = pixel, col = out channel ----
  float* outb = out + (size_t)b * COUT * HW;
  int prow = w0 + wv * 16 + ((lane >> 4) << 2);
#pragma unroll
  for (int nt = 0; nt < 6; ++nt) {
    int ch = nt * 16 + (lane & 15);
    float bv = bias[ch];
    float* op = outb + (size_t)ch * HW + (size_t)h * W + prow;
    float4 o4;
    o4.x = acc[nt][0] + bv;
    o4.y = acc[nt][1] + bv;
    o4.z = acc[nt][2] + bv;
    o4.w = acc[nt][3] + bv;
    *(float4*)op = o4;
  }
}

// ---------------------------------------------------------------------------
extern "C" void kernel_launch(void* const* d_in, const int* in_sizes, int n_in,
                              void* d_out, int out_size, void* d_ws, size_t ws_size,
                              hipStream_t stream) {
  const float* x        = (const float*)d_in[0];
  const float* weight   = (const float*)d_in[1];
  const float* bias     = (const float*)d_in[2];
  const float* offset_w = (const float*)d_in[3];
  const float* offset_b = (const float*)d_in[4];
  const float* mask_w   = (const float*)d_in[5];
  const float* mask_b   = (const float*)d_in[6];
  float* out = (float*)d_out;

  float* offm = (float*)d_ws;                          // 16*27*16384 f32
  float* wAT  = offm + (size_t)BATCH * 27 * HW;        // 96*9*28 f32
  __bf16* wBT_bf = (__bf16*)(wAT + CIN * 9 * 28);      // 9*96*96 bf16

  const int nPrep = CIN * 9 * 28 + 9 * CIN * COUT;
  prep_weights<<<(nPrep + 255) / 256, 256, 0, stream>>>(weight, offset_w, mask_w, wAT, wBT_bf);
  offmask_kernel<<<BATCH * (H / 2), 256, 0, stream>>>(x, wAT, offset_b, mask_b, offm);
  deform_kernel<<<BATCH * H * (W / 64), 256, 0, stream>>>(x, offm, wBT_bf, bias, out);
}